// Round 1
// baseline (189.829 us; speedup 1.0000x reference)
//
#include <hip/hip_runtime.h>

#define N_TOT 8192
#define DIMS  512

typedef __attribute__((ext_vector_type(8))) short bf16x8;
typedef __attribute__((ext_vector_type(4))) float f32x4;

static __device__ inline unsigned short f2bf(float f) {
    unsigned u = __float_as_uint(f);
    unsigned r = (u + 0x7fffu + ((u >> 16) & 1u)) >> 16;
    return (unsigned short)r;
}

// Kernel 1: convert to bf16, per-row sum of squares (fp32), per-block column sums
// and per-block sum-of-squares partials.  512 blocks x 256 threads, 16 rows/block.
__global__ __launch_bounds__(256) void prep_kernel(
    const float* __restrict__ src, const float* __restrict__ tgt,
    unsigned short* __restrict__ Tb, float* __restrict__ sq,
    float* __restrict__ colpart, float* __restrict__ sumsqpart)
{
    __shared__ float cp[4 * 512];
    __shared__ float wss[4];
    int lane = threadIdx.x & 63;
    int wave = threadIdx.x >> 6;
    int b = blockIdx.x;

    float colacc[8];
#pragma unroll
    for (int j = 0; j < 8; j++) colacc[j] = 0.f;
    float wsum = 0.f;

#pragma unroll
    for (int rr = 0; rr < 4; rr++) {
        int row = b * 16 + wave * 4 + rr;
        const float* p = (row < 4096) ? (src + (size_t)row * DIMS)
                                      : (tgt + (size_t)(row - 4096) * DIMS);
        float4 v0 = *(const float4*)(p + lane * 8);
        float4 v1 = *(const float4*)(p + lane * 8 + 4);
        float vs[8] = {v0.x, v0.y, v0.z, v0.w, v1.x, v1.y, v1.z, v1.w};
        float rs = 0.f;
        unsigned out[4];
#pragma unroll
        for (int j = 0; j < 8; j++) { rs += vs[j] * vs[j]; colacc[j] += vs[j]; }
#pragma unroll
        for (int j = 0; j < 4; j++)
            out[j] = (unsigned)f2bf(vs[2 * j]) | ((unsigned)f2bf(vs[2 * j + 1]) << 16);
        *(uint4*)(Tb + (size_t)row * DIMS + lane * 8) = make_uint4(out[0], out[1], out[2], out[3]);
#pragma unroll
        for (int off = 32; off; off >>= 1) rs += __shfl_down(rs, off, 64);
        if (lane == 0) { sq[row] = rs; wsum += rs; }
    }
    if (lane == 0) wss[wave] = wsum;
#pragma unroll
    for (int j = 0; j < 8; j++) cp[wave * 512 + lane * 8 + j] = colacc[j];
    __syncthreads();
    int t = threadIdx.x;
    float c0 = cp[t] + cp[512 + t] + cp[1024 + t] + cp[1536 + t];
    float c1 = cp[t + 256] + cp[512 + t + 256] + cp[1024 + t + 256] + cp[1536 + t + 256];
    colpart[(size_t)b * 512 + t] = c0;
    colpart[(size_t)b * 512 + t + 256] = c1;
    if (t == 0) sumsqpart[b] = wss[0] + wss[1] + wss[2] + wss[3];
}

// Kernel 2: bandwidth = (2*N*sum(sq) - 2*||colsum||^2) / (N^2-N) / 4   (fp64)
__global__ __launch_bounds__(512) void bw_kernel(
    const float* __restrict__ colpart, const float* __restrict__ sumsqpart,
    double* __restrict__ bwout)
{
    int t = threadIdx.x;  // 512 threads
    float cs = 0.f;
    for (int b = 0; b < 512; b++) cs += colpart[b * 512 + t];
    double c2 = (double)cs * (double)cs;
    double ss = (double)sumsqpart[t];
#pragma unroll
    for (int off = 32; off; off >>= 1) {
        c2 += __shfl_down(c2, off, 64);
        ss += __shfl_down(ss, off, 64);
    }
    __shared__ double rc[8], rs[8];
    if ((t & 63) == 0) { rc[t >> 6] = c2; rs[t >> 6] = ss; }
    __syncthreads();
    if (t == 0) {
        double C2 = 0.0, SS = 0.0;
        for (int w = 0; w < 8; w++) { C2 += rc[w]; SS += rs[w]; }
        double suml2 = 2.0 * 8192.0 * SS - 2.0 * C2;
        double denom = 8192.0 * 8192.0 - 8192.0;
        bwout[0] = suml2 / denom / 4.0;  // kernel_mul^(kernel_num//2) = 4
    }
}

// Kernel 3: main fused pairwise-kernel tile. Upper triangle of 64x64 tile grid,
// 128x128 tile, BK=32, 4 waves (2x2), 4x4 mfma_f32_16x16x32_bf16 per wave.
__global__ __launch_bounds__(256) void mmd_main(
    const unsigned short* __restrict__ Tb, const float* __restrict__ sq,
    const double* __restrict__ bwp, double* __restrict__ partial)
{
    int J = blockIdx.x, I = blockIdx.y;
    if (I > J) return;  // symmetry: upper triangle only

    __shared__ __align__(16) unsigned short As[128 * 32];
    __shared__ __align__(16) unsigned short Bs[128 * 32];
    __shared__ float sqA[128], sqB[128];
    __shared__ float wsum[4];

    int t = threadIdx.x;
    int lane = t & 63, wave = t >> 6;
    int wr = (wave >> 1) * 64, wc = (wave & 1) * 64;
    int m = lane & 15, quad = lane >> 4;

    if (t < 128) sqA[t] = sq[I * 128 + t];
    else         sqB[t - 128] = sq[J * 128 + (t - 128)];

    f32x4 acc[4][4] = {};

    const unsigned short* Arow = Tb + (size_t)I * 128 * DIMS;
    const unsigned short* Brow = Tb + (size_t)J * 128 * DIMS;
    int ldrow = wave * 16 + (lane >> 2);  // 0..63 row within 64-row stage slab
    int ldcol = (lane & 3) * 8;           // element offset (16B granules)

    for (int k0 = 0; k0 < 512; k0 += 32) {
#pragma unroll
        for (int p = 0; p < 2; p++) {
            int r = p * 64 + ldrow;
            const unsigned short* ga = Arow + (size_t)r * DIMS + k0 + ldcol;
            const unsigned short* gb = Brow + (size_t)r * DIMS + k0 + ldcol;
            __builtin_amdgcn_global_load_lds(
                (const __attribute__((address_space(1))) void*)ga,
                (__attribute__((address_space(3))) void*)&As[(p * 64 + wave * 16) * 32], 16, 0, 0);
            __builtin_amdgcn_global_load_lds(
                (const __attribute__((address_space(1))) void*)gb,
                (__attribute__((address_space(3))) void*)&Bs[(p * 64 + wave * 16) * 32], 16, 0, 0);
        }
        __syncthreads();
        bf16x8 af[4], bfr[4];
#pragma unroll
        for (int mi = 0; mi < 4; mi++)
            af[mi] = *(const bf16x8*)&As[(wr + mi * 16 + m) * 32 + quad * 8];
#pragma unroll
        for (int ni = 0; ni < 4; ni++)
            bfr[ni] = *(const bf16x8*)&Bs[(wc + ni * 16 + m) * 32 + quad * 8];
#pragma unroll
        for (int mi = 0; mi < 4; mi++)
#pragma unroll
            for (int ni = 0; ni < 4; ni++)
                acc[mi][ni] = __builtin_amdgcn_mfma_f32_16x16x32_bf16(
                    af[mi], bfr[ni], acc[mi][ni], 0, 0, 0);
        __syncthreads();
    }

    // Epilogue: l2 -> 5-bandwidth Gaussian sum, diagonal forced to exactly 5.0
    float c_base = (float)(1.0 / bwp[0]);
    float lsum = 0.f;
    bool diag = (I == J);
#pragma unroll
    for (int mi = 0; mi < 4; mi++) {
#pragma unroll
        for (int ni = 0; ni < 4; ni++) {
#pragma unroll
            for (int r = 0; r < 4; r++) {
                float dot = acc[mi][ni][r];
                int rl = wr + mi * 16 + quad * 4 + r;  // C row = A-side index
                int cl = wc + ni * 16 + m;             // C col = B-side index
                float l2 = sqA[rl] + sqB[cl] - 2.0f * dot;
                l2 = fmaxf(l2, 0.f);
                float kv;
                if (diag && rl == cl) {
                    kv = 5.0f;
                } else {
                    float c = c_base;
                    kv = 0.f;
#pragma unroll
                    for (int i = 0; i < 5; i++) { kv += __expf(-l2 * c); c *= 0.5f; }
                }
                lsum += kv;
            }
        }
    }
#pragma unroll
    for (int off = 32; off; off >>= 1) lsum += __shfl_down(lsum, off, 64);
    if (lane == 0) wsum[wave] = lsum;
    __syncthreads();
    if (t == 0) {
        double s = (double)wsum[0] + (double)wsum[1] + (double)wsum[2] + (double)wsum[3];
        double wgt = diag ? 1.0 : 2.0;                 // off-diagonal tiles count twice
        bool cross = (I < 32) != (J < 32);             // xy/yx quadrant -> negative sign
        partial[I * 64 + J] = s * wgt * (cross ? -1.0 : 1.0);
    }
}

// Kernel 4: reduce per-tile partials -> scalar result
__global__ __launch_bounds__(256) void final_kernel(
    const double* __restrict__ partial, float* __restrict__ out)
{
    int t = threadIdx.x;
    double s = 0.0;
    for (int idx = t; idx < 4096; idx += 256) {
        int I2 = idx >> 6, J2 = idx & 63;
        if (I2 <= J2) s += partial[idx];
    }
#pragma unroll
    for (int off = 32; off; off >>= 1) s += __shfl_down(s, off, 64);
    __shared__ double red[4];
    if ((t & 63) == 0) red[t >> 6] = s;
    __syncthreads();
    if (t == 0) {
        double tot = red[0] + red[1] + red[2] + red[3];
        out[0] = (float)(tot / (4096.0 * 4096.0));
    }
}

extern "C" void kernel_launch(void* const* d_in, const int* in_sizes, int n_in,
                              void* d_out, int out_size, void* d_ws, size_t ws_size,
                              hipStream_t stream) {
    const float* src = (const float*)d_in[0];
    const float* tgt = (const float*)d_in[1];
    char* ws = (char*)d_ws;
    unsigned short* Tb   = (unsigned short*)ws;                          // 8 MiB bf16 [8192][512]
    float* sq            = (float*)(ws + 8u * 1024 * 1024);              // 32 KiB
    float* colpart       = (float*)(ws + 8u * 1024 * 1024 + 32 * 1024);  // 1 MiB [512][512]
    float* sumsqpart     = (float*)(ws + 9u * 1024 * 1024 + 32 * 1024);  // 2 KiB
    double* bw           = (double*)(ws + 9u * 1024 * 1024 + 64 * 1024); // 8 B
    double* partial      = (double*)(ws + 9u * 1024 * 1024 + 64 * 1024 + 256); // 32 KiB

    prep_kernel<<<512, 256, 0, stream>>>(src, tgt, Tb, sq, colpart, sumsqpart);
    bw_kernel<<<1, 512, 0, stream>>>(colpart, sumsqpart, bw);
    mmd_main<<<dim3(64, 64), 256, 0, stream>>>(Tb, sq, bw, partial);
    final_kernel<<<1, 256, 0, stream>>>(partial, (float*)d_out);
}

// Round 2
// 151.620 us; speedup vs baseline: 1.2520x; 1.2520x over previous
//
#include <hip/hip_runtime.h>

#define N_TOT 8192
#define DIMS  512

typedef __attribute__((ext_vector_type(8))) short bf16x8;
typedef __attribute__((ext_vector_type(4))) float f32x4;

static __device__ inline unsigned short f2bf(float f) {
    unsigned u = __float_as_uint(f);
    unsigned r = (u + 0x7fffu + ((u >> 16) & 1u)) >> 16;
    return (unsigned short)r;
}

// Kernel 1: convert to bf16, per-row sum of squares (fp32), per-block column sums
// and per-block sum-of-squares partials.  512 blocks x 256 threads, 16 rows/block.
__global__ __launch_bounds__(256) void prep_kernel(
    const float* __restrict__ src, const float* __restrict__ tgt,
    unsigned short* __restrict__ Tb, float* __restrict__ sq,
    float* __restrict__ colpart, float* __restrict__ sumsqpart)
{
    __shared__ float cp[4 * 512];
    __shared__ float wss[4];
    int lane = threadIdx.x & 63;
    int wave = threadIdx.x >> 6;
    int b = blockIdx.x;

    float colacc[8];
#pragma unroll
    for (int j = 0; j < 8; j++) colacc[j] = 0.f;
    float wsum = 0.f;

#pragma unroll
    for (int rr = 0; rr < 4; rr++) {
        int row = b * 16 + wave * 4 + rr;
        const float* p = (row < 4096) ? (src + (size_t)row * DIMS)
                                      : (tgt + (size_t)(row - 4096) * DIMS);
        float4 v0 = *(const float4*)(p + lane * 8);
        float4 v1 = *(const float4*)(p + lane * 8 + 4);
        float vs[8] = {v0.x, v0.y, v0.z, v0.w, v1.x, v1.y, v1.z, v1.w};
        float rs = 0.f;
        unsigned out[4];
#pragma unroll
        for (int j = 0; j < 8; j++) { rs += vs[j] * vs[j]; colacc[j] += vs[j]; }
#pragma unroll
        for (int j = 0; j < 4; j++)
            out[j] = (unsigned)f2bf(vs[2 * j]) | ((unsigned)f2bf(vs[2 * j + 1]) << 16);
        *(uint4*)(Tb + (size_t)row * DIMS + lane * 8) = make_uint4(out[0], out[1], out[2], out[3]);
#pragma unroll
        for (int off = 32; off; off >>= 1) rs += __shfl_down(rs, off, 64);
        if (lane == 0) { sq[row] = rs; wsum += rs; }
    }
    if (lane == 0) wss[wave] = wsum;
#pragma unroll
    for (int j = 0; j < 8; j++) cp[wave * 512 + lane * 8 + j] = colacc[j];
    __syncthreads();
    int t = threadIdx.x;
    float c0 = cp[t] + cp[512 + t] + cp[1024 + t] + cp[1536 + t];
    float c1 = cp[t + 256] + cp[512 + t + 256] + cp[1024 + t + 256] + cp[1536 + t + 256];
    colpart[(size_t)b * 512 + t] = c0;
    colpart[(size_t)b * 512 + t + 256] = c1;
    if (t == 0) sumsqpart[b] = wss[0] + wss[1] + wss[2] + wss[3];
}

// Kernel 2a: parallel column-sum reduction 512 slabs -> 8 slabs.
// 16 blocks x 256 threads; block g covers columns (g&1)*256.. and b-slab g>>1.
__global__ __launch_bounds__(256) void bw1_kernel(
    const float* __restrict__ colpart, float* __restrict__ colpart2)
{
    int g = blockIdx.x, t = threadIdx.x;
    int c = (g & 1) * 256 + t;
    int b0 = (g >> 1) * 64;
    float s0 = 0.f, s1 = 0.f, s2 = 0.f, s3 = 0.f;
#pragma unroll 4
    for (int b = 0; b < 64; b += 4) {
        s0 += colpart[(size_t)(b0 + b) * 512 + c];
        s1 += colpart[(size_t)(b0 + b + 1) * 512 + c];
        s2 += colpart[(size_t)(b0 + b + 2) * 512 + c];
        s3 += colpart[(size_t)(b0 + b + 3) * 512 + c];
    }
    colpart2[(g >> 1) * 512 + c] = (s0 + s1) + (s2 + s3);
}

// Kernel 2b: bandwidth = (2*N*sum(sq) - 2*||colsum||^2) / (N^2-N) / 4   (fp64)
__global__ __launch_bounds__(512) void bw2_kernel(
    const float* __restrict__ colpart2, const float* __restrict__ sumsqpart,
    double* __restrict__ bwout)
{
    int t = threadIdx.x;  // 512 threads
    float cs = 0.f;
#pragma unroll
    for (int s = 0; s < 8; s++) cs += colpart2[s * 512 + t];
    double c2 = (double)cs * (double)cs;
    double ss = (double)sumsqpart[t];
#pragma unroll
    for (int off = 32; off; off >>= 1) {
        c2 += __shfl_down(c2, off, 64);
        ss += __shfl_down(ss, off, 64);
    }
    __shared__ double rc[8], rs[8];
    if ((t & 63) == 0) { rc[t >> 6] = c2; rs[t >> 6] = ss; }
    __syncthreads();
    if (t == 0) {
        double C2 = 0.0, SS = 0.0;
        for (int w = 0; w < 8; w++) { C2 += rc[w]; SS += rs[w]; }
        double suml2 = 2.0 * 8192.0 * SS - 2.0 * C2;
        double denom = 8192.0 * 8192.0 - 8192.0;
        bwout[0] = suml2 / denom / 4.0;  // kernel_mul^(kernel_num//2) = 4
    }
}

// Kernel 3: main fused pairwise-kernel tile. Packed upper-triangle launch
// (2080 blocks), 128x128 tile, BK=32, 4 waves (2x2), 4x4 mfma 16x16x32 bf16.
// XOR granule swizzle in LDS to cut ds_read bank conflicts.
__global__ __launch_bounds__(256) void mmd_main(
    const unsigned short* __restrict__ Tb, const float* __restrict__ sq,
    const double* __restrict__ bwp, double* __restrict__ partial)
{
    // XCD-contiguous reorder: round-robin dispatch (bb%8 = XCD) -> give each
    // XCD a contiguous triangular range for L2 locality.  2080 = 8*260.
    int bb = blockIdx.x;
    int b = (bb & 7) * 260 + (bb >> 3);
    // triangular decode: row I starts at I*(129-I)/2
    int I = (int)((129.0 - sqrt(129.0 * 129.0 - 8.0 * (double)b)) * 0.5);
    while ((I + 1) * (129 - (I + 1)) / 2 <= b) I++;
    while (I * (129 - I) / 2 > b) I--;
    int J = I + (b - I * (129 - I) / 2);

    __shared__ __align__(16) unsigned short As[128 * 32];
    __shared__ __align__(16) unsigned short Bs[128 * 32];
    __shared__ float sqA[128], sqB[128];
    __shared__ float wsum[4];

    int t = threadIdx.x;
    int lane = t & 63, wave = t >> 6;
    int wr = (wave >> 1) * 64, wc = (wave & 1) * 64;
    int m = lane & 15, quad = lane >> 4;
    int qx = (quad ^ (m & 3)) * 8;  // XOR-swizzled granule offset for reads

    if (t < 128) sqA[t] = sq[I * 128 + t];
    else         sqB[t - 128] = sq[J * 128 + (t - 128)];

    double bwv = bwp[0];  // issue early; used only in epilogue

    f32x4 acc[4][4] = {};

    const unsigned short* Arow = Tb + (size_t)I * 128 * DIMS;
    const unsigned short* Brow = Tb + (size_t)J * 128 * DIMS;
    int ldrow = wave * 16 + (lane >> 2);            // row within 64-row slab
    int ldcol = ((lane & 3) ^ (ldrow & 3)) * 8;     // XOR-swizzled source granule

    for (int k0 = 0; k0 < 512; k0 += 32) {
#pragma unroll
        for (int p = 0; p < 2; p++) {
            int r = p * 64 + ldrow;
            const unsigned short* ga = Arow + (size_t)r * DIMS + k0 + ldcol;
            const unsigned short* gb = Brow + (size_t)r * DIMS + k0 + ldcol;
            __builtin_amdgcn_global_load_lds(
                (const __attribute__((address_space(1))) void*)ga,
                (__attribute__((address_space(3))) void*)&As[(p * 64 + wave * 16) * 32], 16, 0, 0);
            __builtin_amdgcn_global_load_lds(
                (const __attribute__((address_space(1))) void*)gb,
                (__attribute__((address_space(3))) void*)&Bs[(p * 64 + wave * 16) * 32], 16, 0, 0);
        }
        __syncthreads();
        bf16x8 af[4], bfr[4];
#pragma unroll
        for (int mi = 0; mi < 4; mi++)
            af[mi] = *(const bf16x8*)&As[(wr + mi * 16 + m) * 32 + qx];
#pragma unroll
        for (int ni = 0; ni < 4; ni++)
            bfr[ni] = *(const bf16x8*)&Bs[(wc + ni * 16 + m) * 32 + qx];
#pragma unroll
        for (int mi = 0; mi < 4; mi++)
#pragma unroll
            for (int ni = 0; ni < 4; ni++)
                acc[mi][ni] = __builtin_amdgcn_mfma_f32_16x16x32_bf16(
                    af[mi], bfr[ni], acc[mi][ni], 0, 0, 0);
        __syncthreads();
    }

    // Epilogue: l2 -> 5-bandwidth Gaussian sum via power chain:
    //   sum_i exp(-t/2^i) = u + u^2 + u^4 + u^8 + u^16,  u = exp(-t/16)
    float c16 = (float)(1.0 / bwv) * 0.0625f;
    float lsum = 0.f;
    bool diag = (I == J);
#pragma unroll
    for (int mi = 0; mi < 4; mi++) {
#pragma unroll
        for (int ni = 0; ni < 4; ni++) {
#pragma unroll
            for (int r = 0; r < 4; r++) {
                float dot = acc[mi][ni][r];
                int rl = wr + mi * 16 + quad * 4 + r;  // C row = A-side index
                int cl = wc + ni * 16 + m;             // C col = B-side index
                float l2 = sqA[rl] + sqB[cl] - 2.0f * dot;
                l2 = fmaxf(l2, 0.f);
                float kv;
                if (diag && rl == cl) {
                    kv = 5.0f;
                } else {
                    float u = __expf(-l2 * c16);
                    float u2 = u * u;
                    float u4 = u2 * u2;
                    float u8 = u4 * u4;
                    float u16 = u8 * u8;
                    kv = ((u + u2) + (u4 + u8)) + u16;
                }
                lsum += kv;
            }
        }
    }
#pragma unroll
    for (int off = 32; off; off >>= 1) lsum += __shfl_down(lsum, off, 64);
    if (lane == 0) wsum[wave] = lsum;
    __syncthreads();
    if (t == 0) {
        double s = (double)wsum[0] + (double)wsum[1] + (double)wsum[2] + (double)wsum[3];
        double wgt = diag ? 1.0 : 2.0;                 // off-diagonal tiles count twice
        bool cross = (I < 32) != (J < 32);             // xy/yx quadrant -> negative sign
        partial[I * 64 + J] = s * wgt * (cross ? -1.0 : 1.0);
    }
}

// Kernel 4: reduce per-tile partials -> scalar result
__global__ __launch_bounds__(256) void final_kernel(
    const double* __restrict__ partial, float* __restrict__ out)
{
    int t = threadIdx.x;
    double s = 0.0;
    for (int idx = t; idx < 4096; idx += 256) {
        int I2 = idx >> 6, J2 = idx & 63;
        if (I2 <= J2) s += partial[idx];
    }
#pragma unroll
    for (int off = 32; off; off >>= 1) s += __shfl_down(s, off, 64);
    __shared__ double red[4];
    if ((t & 63) == 0) red[t >> 6] = s;
    __syncthreads();
    if (t == 0) {
        double tot = red[0] + red[1] + red[2] + red[3];
        out[0] = (float)(tot / (4096.0 * 4096.0));
    }
}

extern "C" void kernel_launch(void* const* d_in, const int* in_sizes, int n_in,
                              void* d_out, int out_size, void* d_ws, size_t ws_size,
                              hipStream_t stream) {
    const float* src = (const float*)d_in[0];
    const float* tgt = (const float*)d_in[1];
    char* ws = (char*)d_ws;
    unsigned short* Tb   = (unsigned short*)ws;                          // 8 MiB bf16 [8192][512]
    float* sq            = (float*)(ws + 8u * 1024 * 1024);              // 32 KiB
    float* colpart       = (float*)(ws + 8u * 1024 * 1024 + 32 * 1024);  // 1 MiB [512][512]
    float* sumsqpart     = (float*)(ws + 9u * 1024 * 1024 + 32 * 1024);  // 2 KiB
    double* bw           = (double*)(ws + 9u * 1024 * 1024 + 64 * 1024); // 8 B
    double* partial      = (double*)(ws + 9u * 1024 * 1024 + 64 * 1024 + 256); // 32 KiB
    float* colpart2      = (float*)(ws + 9u * 1024 * 1024 + 64 * 1024 + 256 + 32 * 1024); // 16 KiB

    prep_kernel<<<512, 256, 0, stream>>>(src, tgt, Tb, sq, colpart, sumsqpart);
    bw1_kernel<<<16, 256, 0, stream>>>(colpart, colpart2);
    bw2_kernel<<<1, 512, 0, stream>>>(colpart2, sumsqpart, bw);
    mmd_main<<<2080, 256, 0, stream>>>(Tb, sq, bw, partial);
    final_kernel<<<1, 256, 0, stream>>>(partial, (float*)d_out);
}